// Round 1
// baseline (76.256 us; speedup 1.0000x reference)
//
#include <hip/hip_runtime.h>

#define GAMMA 0.1f

constexpr int MTOT = 65536;
constexpr int NTOT = 1024;
constexpr int KDIM = 64;
constexpr int BM = 128;
constexpr int BN = 128;

using frag_ab = __attribute__((ext_vector_type(8))) short;  // 8 bf16 (4 VGPRs)
using f32x4   = __attribute__((ext_vector_type(4))) float;  // 4 f32 acc

// f32 -> bf16 round-to-nearest-even, also returns the value rounded back to f32.
__device__ __forceinline__ ushort bf16_rne(float x, float& back) {
  unsigned u = __float_as_uint(x);
  unsigned r = (u + 0x7FFFu + ((u >> 16) & 1u)) >> 16;
  back = __uint_as_float(r << 16);
  return (ushort)r;
}

// Stage a [128 rows x 64 cols] f32 tile into bf16 hi/lo LDS arrays (XOR-swizzled),
// and write per-row squared norms (from the exact f32 data) into sq[128].
// 256 threads, 8 consecutive f32 per thread per pass, 4 passes.
__device__ __forceinline__ void stage_tile(const float* __restrict__ src,
                                           ushort* hi, ushort* lo, float* sq,
                                           int tid) {
  #pragma unroll
  for (int pass = 0; pass < 4; ++pass) {
    const int idx = pass * 2048 + tid * 8;   // flat element index in tile
    const int row = idx >> 6;                // /64
    const int s   = tid & 7;                 // 16B slot within the 128B row
    const float4* p = reinterpret_cast<const float4*>(src + idx);
    float4 v0 = p[0];
    float4 v1 = p[1];
    float v[8] = {v0.x, v0.y, v0.z, v0.w, v1.x, v1.y, v1.z, v1.w};
    frag_ab hv, lv;
    float ss = 0.0f;
    #pragma unroll
    for (int i = 0; i < 8; ++i) {
      float back;
      ushort hb = bf16_rne(v[i], back);
      float back2;
      ushort lb = bf16_rne(v[i] - back, back2);
      (void)back2;
      ss += v[i] * v[i];
      hv[i] = (short)hb;
      lv[i] = (short)lb;
    }
    // 8 lanes share a row (lanes t..t^7 within one octet of the wave)
    ss += __shfl_xor(ss, 1);
    ss += __shfl_xor(ss, 2);
    ss += __shfl_xor(ss, 4);
    if (s == 0) sq[row] = ss;
    const int slot = s ^ (row & 7);  // bank-conflict XOR swizzle (G4)
    *reinterpret_cast<frag_ab*>(hi + row * 64 + slot * 8) = hv;
    *reinterpret_cast<frag_ab*>(lo + row * 64 + slot * 8) = lv;
  }
}

__global__ __launch_bounds__(256, 2)
void rbf_mfma_kernel(const float* __restrict__ x,
                     const float* __restrict__ centers,
                     float* __restrict__ out) {
  __shared__ ushort sAhi[BM * 64];
  __shared__ ushort sAlo[BM * 64];
  __shared__ ushort sBhi[BN * 64];
  __shared__ ushort sBlo[BN * 64];
  __shared__ float  sAsq[BM];
  __shared__ float  sBsq[BN];

  const int tid = threadIdx.x;
  const int mt = blockIdx.x >> 3;   // 512 m-tiles
  const int nt = blockIdx.x & 7;    // 8 n-tiles (adjacent blocks share the x-tile)

  stage_tile(x       + (size_t)mt * BM * KDIM, sAhi, sAlo, sAsq, tid);
  stage_tile(centers + (size_t)nt * BN * KDIM, sBhi, sBlo, sBsq, tid);
  __syncthreads();

  const int lane = tid & 63;
  const int wave = tid >> 6;
  const int wr = wave >> 1;        // wave row 0..1   (64 rows each)
  const int wc = wave & 1;         // wave col 0..1   (64 cols each)
  const int r16 = lane & 15;
  const int g   = lane >> 4;       // 0..3 k-group

  f32x4 acc[4][4] = {};

  #pragma unroll
  for (int ks = 0; ks < 2; ++ks) {
    const int slot = (ks * 4 + g) ^ (r16 & 7);   // matches staging swizzle
    frag_ab ah[4], al[4], bh[4], bl[4];
    #pragma unroll
    for (int m = 0; m < 4; ++m) {
      const int row = wr * 64 + m * 16 + r16;
      ah[m] = *reinterpret_cast<const frag_ab*>(sAhi + row * 64 + slot * 8);
      al[m] = *reinterpret_cast<const frag_ab*>(sAlo + row * 64 + slot * 8);
    }
    #pragma unroll
    for (int n = 0; n < 4; ++n) {
      const int row = wc * 64 + n * 16 + r16;
      bh[n] = *reinterpret_cast<const frag_ab*>(sBhi + row * 64 + slot * 8);
      bl[n] = *reinterpret_cast<const frag_ab*>(sBlo + row * 64 + slot * 8);
    }
    #pragma unroll
    for (int m = 0; m < 4; ++m) {
      #pragma unroll
      for (int n = 0; n < 4; ++n) {
        // cross = xh*ch + xh*cl + xl*ch  (lo*lo dropped, ~1e-6 rel)
        acc[m][n] = __builtin_amdgcn_mfma_f32_16x16x32_bf16(ah[m], bh[n], acc[m][n], 0, 0, 0);
        acc[m][n] = __builtin_amdgcn_mfma_f32_16x16x32_bf16(ah[m], bl[n], acc[m][n], 0, 0, 0);
        acc[m][n] = __builtin_amdgcn_mfma_f32_16x16x32_bf16(al[m], bh[n], acc[m][n], 0, 0, 0);
      }
    }
  }

  // Epilogue: out = exp(-g * max(xsq + csq - 2*cross, 0))
  float csq[4];
  #pragma unroll
  for (int n = 0; n < 4; ++n) csq[n] = sBsq[wc * 64 + n * 16 + r16];

  const size_t row0 = (size_t)mt * BM;
  const int col0 = nt * BN + wc * 64;

  #pragma unroll
  for (int m = 0; m < 4; ++m) {
    #pragma unroll
    for (int r = 0; r < 4; ++r) {
      const int rl = wr * 64 + m * 16 + g * 4 + r;   // local out row
      const float xs = sAsq[rl];
      float* orow = out + (row0 + rl) * (size_t)NTOT + col0;
      #pragma unroll
      for (int n = 0; n < 4; ++n) {
        float l2 = fmaxf(xs + csq[n] - 2.0f * acc[m][n][r], 0.0f);
        orow[n * 16 + r16] = __expf(-GAMMA * l2);
      }
    }
  }
}

extern "C" void kernel_launch(void* const* d_in, const int* in_sizes, int n_in,
                              void* d_out, int out_size, void* d_ws, size_t ws_size,
                              hipStream_t stream) {
  (void)in_sizes; (void)n_in; (void)d_ws; (void)ws_size; (void)out_size;
  const float* x       = (const float*)d_in[0];
  const float* centers = (const float*)d_in[1];
  float* out = (float*)d_out;
  const int grid = (MTOT / BM) * (NTOT / BN);   // 512 * 8 = 4096
  rbf_mfma_kernel<<<grid, 256, 0, stream>>>(x, centers, out);
}